// Round 6
// baseline (425.228 us; speedup 1.0000x reference)
//
#include <hip/hip_runtime.h>

#define IN_F   100
#define HID_F  128
#define OUT_F  47
#define NPART  4     // source partitions (by src & 3); slice = 12.8/4 = 3.2 MB -> fits 4 MB XCD L2

typedef short bf16x8 __attribute__((ext_vector_type(8)));
typedef float f32x4  __attribute__((ext_vector_type(4)));
typedef unsigned short u16;
typedef unsigned int   u32;

__device__ __forceinline__ u16 f2bf(float f) {
    u32 u = __float_as_uint(f);
    u += 0x7FFFu + ((u >> 16) & 1u);           // RNE
    return (u16)(u >> 16);
}
__device__ __forceinline__ float bf2f(u16 b) { return __uint_as_float(((u32)b) << 16); }
__device__ __forceinline__ float lo2f(u32 v) { return __uint_as_float(v << 16); }
__device__ __forceinline__ float hi2f(u32 v) { return __uint_as_float(v & 0xFFFF0000u); }

// ---------------------------------------------------------------------------
// Sub-CSR build: bins = dst*4 + (src&3)
// ---------------------------------------------------------------------------
__global__ void count4_kernel(const int* __restrict__ row, const int* __restrict__ col,
                              int E, int* __restrict__ cnt4) {
    int e = blockIdx.x * blockDim.x + threadIdx.x;
    if (e < E) atomicAdd(&cnt4[row[e] * NPART + (col[e] & 3)], 1);
}

__global__ void dis_kernel(const int* __restrict__ cnt4, float* __restrict__ dis, int N) {
    int i = blockIdx.x * blockDim.x + threadIdx.x;
    if (i < N) {
        int d = cnt4[4 * i] + cnt4[4 * i + 1] + cnt4[4 * i + 2] + cnt4[4 * i + 3];
        dis[i] = rsqrtf((float)d + 1.0f);   // +1 self loop
    }
}

// phase 1: per-1024-block sums (M = 4N = 200000 -> 196 blocks)
__global__ __launch_bounds__(1024) void scan_bsum_kernel(const int* __restrict__ v,
                                                         int* __restrict__ bsum, int M) {
    __shared__ int red[16];
    int i = blockIdx.x * 1024 + threadIdx.x;
    int x = (i < M) ? v[i] : 0;
#pragma unroll
    for (int m = 32; m >= 1; m >>= 1) x += __shfl_xor(x, m, 64);
    if ((threadIdx.x & 63) == 0) red[threadIdx.x >> 6] = x;
    __syncthreads();
    if (threadIdx.x == 0) {
        int s = 0;
#pragma unroll
        for (int j = 0; j < 16; ++j) s += red[j];
        bsum[blockIdx.x] = s;
    }
}

// phase 2: exclusive scan of <=256 block sums
__global__ void scan_mid_kernel(int* __restrict__ bsum, int nb) {
    __shared__ int s[256];
    int t = threadIdx.x;
    int v = (t < nb) ? bsum[t] : 0;
    s[t] = v;
    __syncthreads();
    for (int o = 1; o < 256; o <<= 1) {
        int u = (t >= o) ? s[t - o] : 0;
        __syncthreads();
        s[t] += u;
        __syncthreads();
    }
    if (t < nb) bsum[t] = s[t] - v;     // exclusive
}

// phase 3: per-block exclusive scan + block prefix
__global__ __launch_bounds__(1024) void scan_offs_kernel(const int* __restrict__ v,
                                                         const int* __restrict__ bsum,
                                                         int* __restrict__ offs, int M, int E) {
    __shared__ int s[1024];
    int b = blockIdx.x, t = threadIdx.x;
    int i = b * 1024 + t;
    int val = (i < M) ? v[i] : 0;
    s[t] = val;
    __syncthreads();
    for (int o = 1; o < 1024; o <<= 1) {
        int u = (t >= o) ? s[t - o] : 0;
        __syncthreads();
        s[t] += u;
        __syncthreads();
    }
    if (i < M) offs[i] = bsum[b] + s[t] - val;
    if (b == 0 && t == 0) offs[M] = E;
}

__global__ void fill4_kernel(const int* __restrict__ row, const int* __restrict__ col, int E,
                             const int* __restrict__ offs4, int* __restrict__ fill4,
                             const float* __restrict__ dis,
                             int* __restrict__ ccol4, float* __restrict__ cw4) {
    int e = blockIdx.x * blockDim.x + threadIdx.x;
    if (e < E) {
        int r = row[e], c = col[e];
        int bin = r * NPART + (c & 3);
        int pos = offs4[bin] + atomicAdd(&fill4[bin], 1);
        ccol4[pos] = c;
        cw4[pos]   = dis[r] * dis[c];
    }
}

// ---------------------------------------------------------------------------
// Weight prep: B = [ Wa^T ; Wx^T ] as [2*NPAD][128] hi/lo
// ---------------------------------------------------------------------------
__global__ void wtprep_all_kernel(const float* __restrict__ W1, const float* __restrict__ W2,
                                  const float* __restrict__ W3,
                                  u16* __restrict__ B1h, u16* __restrict__ B1l,
                                  u16* __restrict__ B2h, u16* __restrict__ B2l,
                                  u16* __restrict__ B3h, u16* __restrict__ B3l) {
    int b = blockIdx.x, k = threadIdx.x;   // k: 0..127
    const float* W; u16 *Bh, *Bl; int KSRC, NSRC, NPAD, n;
    if (b < 256)      { W = W1; Bh = B1h; Bl = B1l; KSRC = IN_F;  NSRC = HID_F; NPAD = 128; n = b; }
    else if (b < 512) { W = W2; Bh = B2h; Bl = B2l; KSRC = HID_F; NSRC = HID_F; NPAD = 128; n = b - 256; }
    else              { W = W3; Bh = B3h; Bl = B3l; KSRC = HID_F; NSRC = OUT_F; NPAD = 48;  n = b - 512; }
    int half = (n >= NPAD) ? 1 : 0;
    int cc = n - half * NPAD;
    float v = (cc < NSRC && k < KSRC) ? W[(size_t)(half * KSRC + k) * NSRC + cc] : 0.f;
    u16 h = f2bf(v);
    Bh[(size_t)n * 128 + k] = h;
    Bl[(size_t)n * 128 + k] = f2bf(v - bf2f(h));
}

// ---------------------------------------------------------------------------
// Layer-1 GEMM: stage x tile -> LDS hi/lo, [y|z] = A @ B^T
// ---------------------------------------------------------------------------
__global__ __launch_bounds__(1024) void xgemm_kernel(
    const float* __restrict__ x,
    const u16* __restrict__ Bh, const u16* __restrict__ Bl,
    u16* __restrict__ yout, float* __restrict__ zout, int N) {
    constexpr int STR = 152;
    __shared__ u16 sA[2][16 * STR];
    int tid = threadIdx.x;
    int m0 = blockIdx.x * 16;
    int w = tid >> 6, lane = tid & 63;

#pragma unroll
    for (int idx = tid; idx < 16 * 128; idx += 1024) {
        int r = idx >> 7, c = idx & 127;
        float v = (c < IN_F) ? x[(size_t)(m0 + r) * IN_F + c] : 0.f;
        u16 h = f2bf(v);
        sA[0][r * STR + c] = h;
        sA[1][r * STR + c] = f2bf(v - bf2f(h));
    }
    __syncthreads();

    if (w < 16) {
        int c16 = lane & 15, g = lane >> 4, koff = g * 8;
        const u16* pah = &sA[0][c16 * STR + koff];
        const u16* pal = &sA[1][c16 * STR + koff];
        const u16* pbh = Bh + (size_t)(w * 16 + c16) * 128 + koff;
        const u16* pbl = Bl + (size_t)(w * 16 + c16) * 128 + koff;
        f32x4 acc = (f32x4){0.f, 0.f, 0.f, 0.f};
#pragma unroll
        for (int kk = 0; kk < 128; kk += 32) {
            bf16x8 ah = *(const bf16x8*)(pah + kk);
            bf16x8 al = *(const bf16x8*)(pal + kk);
            bf16x8 bh = *(const bf16x8*)(pbh + kk);
            bf16x8 bl = *(const bf16x8*)(pbl + kk);
            acc = __builtin_amdgcn_mfma_f32_16x16x32_bf16(ah, bh, acc, 0, 0, 0);
            acc = __builtin_amdgcn_mfma_f32_16x16x32_bf16(al, bh, acc, 0, 0, 0);
            acc = __builtin_amdgcn_mfma_f32_16x16x32_bf16(ah, bl, acc, 0, 0, 0);
        }
        if (w < 8) {
            int col = w * 16 + c16;
#pragma unroll
            for (int r = 0; r < 4; ++r)
                yout[(size_t)(m0 + g * 4 + r) * 128 + col] = f2bf(acc[r]);
        } else {
            int col = (w - 8) * 16 + c16;
#pragma unroll
            for (int r = 0; r < 4; ++r)
                zout[(size_t)(m0 + g * 4 + r) * 128 + col] = acc[r];
        }
    }
}

// ---------------------------------------------------------------------------
// Partitioned gather: block -> (tile of 4 nodes, partition p); bid%8 pins
// partition p = (bid&7)&3 to one XCD pair so slice p (3.2 MB) is L2-resident.
// Wave = node; lane = (eg, seg); writes partial[p][node][NDW*2] bf16.
// ---------------------------------------------------------------------------
template <int NDW>   // dwords per y row: 64 (128 cols) or 32 (64 cols)
__global__ __launch_bounds__(256) void pgather_kernel(
    const u16* __restrict__ yin, const int* __restrict__ offs4,
    const int* __restrict__ ccol4, const float* __restrict__ cw4,
    u16* __restrict__ partial, int N) {
    constexpr int SEGS = NDW / 4;       // int4 segments per row (16 or 8)
    constexpr int EGS  = 64 / SEGS;     // concurrent edges (4 or 8)
    int bid = blockIdx.x;
    int q = bid & 7;
    int p = q & 3;
    int t = (bid >> 3) * 2 + (q >> 2);
    int w = threadIdx.x >> 6, lane = threadIdx.x & 63;
    int node = t * 4 + w;
    if (node >= N) return;
    int seg = lane % SEGS, eg = lane / SEGS;

    float a[8];
#pragma unroll
    for (int j = 0; j < 8; ++j) a[j] = 0.f;

    int bin = node * NPART + p;
    int s = offs4[bin], e = offs4[bin + 1];
#pragma unroll 2
    for (int p0 = s; p0 < e; p0 += EGS) {
        int idx = p0 + eg;
        int idc = min(idx, e - 1);
        int c   = ccol4[idc];
        float wt = (idx < e) ? cw4[idc] : 0.f;
        int4 v = *(const int4*)(yin + (size_t)c * (NDW * 2) + seg * 8);
        a[0] += wt * lo2f(v.x); a[1] += wt * hi2f(v.x);
        a[2] += wt * lo2f(v.y); a[3] += wt * hi2f(v.y);
        a[4] += wt * lo2f(v.z); a[5] += wt * hi2f(v.z);
        a[6] += wt * lo2f(v.w); a[7] += wt * hi2f(v.w);
    }

#pragma unroll
    for (int j = 0; j < 8; ++j) {
#pragma unroll
        for (int m = SEGS; m < 64; m <<= 1) a[j] += __shfl_xor(a[j], m, 64);
    }
    if (eg == 0) {
        bf16x8 hv;
#pragma unroll
        for (int j = 0; j < 8; ++j) hv[j] = (short)f2bf(a[j]);
        *(bf16x8*)(partial + ((size_t)p * N + node) * (NDW * 2) + seg * 8) = hv;
    }
}

// ---------------------------------------------------------------------------
// Reduce partials + z + diag-self, LayerNorm+ReLU -> LDS, then MFMA GEMM.
// ---------------------------------------------------------------------------
template <int HOUT, int YSTR>
__global__ __launch_bounds__(1024) void reduce_ln_gemm_kernel(
    const u16* __restrict__ yself, const float* __restrict__ zin,
    const u16* __restrict__ partial, const float* __restrict__ dis,
    const u16* __restrict__ Bh, const u16* __restrict__ Bl,
    u16* __restrict__ yout, float* __restrict__ zout, int N) {
    constexpr int STR = 152;
    __shared__ u16 sA[2][16 * STR];
    int tid = threadIdx.x;
    int m0 = blockIdx.x * 16;
    int w = tid >> 6, lane = tid & 63;
    int node = m0 + w;
    int seg = lane & 15, pg = lane >> 4;

    float a[8];
    {   // each 16-lane group reads one partition's partial row
        int4 v = *(const int4*)(partial + ((size_t)pg * N + node) * 128 + seg * 8);
        a[0] = lo2f(v.x); a[1] = hi2f(v.x);
        a[2] = lo2f(v.y); a[3] = hi2f(v.y);
        a[4] = lo2f(v.z); a[5] = hi2f(v.z);
        a[6] = lo2f(v.w); a[7] = hi2f(v.w);
    }
#pragma unroll
    for (int j = 0; j < 8; ++j) {
        a[j] += __shfl_xor(a[j], 16, 64);
        a[j] += __shfl_xor(a[j], 32, 64);
    }
    if (pg == 0) {     // z + diag-enhanced self loop
        float d = dis[node];
        float sw = 2.f * d * d;
        int4   sv = *(const int4*)  (yself + (size_t)node * 128 + seg * 8);
        float4 z0 = *(const float4*)(zin + (size_t)node * 128 + seg * 8);
        float4 z1 = *(const float4*)(zin + (size_t)node * 128 + seg * 8 + 4);
        a[0] += z0.x + sw * lo2f(sv.x); a[1] += z0.y + sw * hi2f(sv.x);
        a[2] += z0.z + sw * lo2f(sv.y); a[3] += z0.w + sw * hi2f(sv.y);
        a[4] += z1.x + sw * lo2f(sv.z); a[5] += z1.y + sw * hi2f(sv.z);
        a[6] += z1.z + sw * lo2f(sv.w); a[7] += z1.w + sw * hi2f(sv.w);
    }
    // LN stats (valid on pg==0 lanes)
    float s1 = 0.f, s2 = 0.f;
#pragma unroll
    for (int j = 0; j < 8; ++j) { s1 += a[j]; s2 += a[j] * a[j]; }
#pragma unroll
    for (int m = 8; m >= 1; m >>= 1) {
        s1 += __shfl_xor(s1, m, 64);
        s2 += __shfl_xor(s2, m, 64);
    }
    float mu  = s1 * (1.0f / 128);
    float var = s2 * (1.0f / 128) - mu * mu;
    float inv = rsqrtf(var + 1e-5f);
    if (pg == 0) {
        bf16x8 hv, lv;
#pragma unroll
        for (int j = 0; j < 8; ++j) {
            float o = fmaxf((a[j] - mu) * inv, 0.f);
            u16 h = f2bf(o);
            hv[j] = (short)h;
            lv[j] = (short)f2bf(o - bf2f(h));
        }
        *(bf16x8*)(&sA[0][w * STR + seg * 8]) = hv;
        *(bf16x8*)(&sA[1][w * STR + seg * 8]) = lv;
    }
    __syncthreads();

    // GEMM phase: wave w -> output tile w over [y|z] (2*HOUT cols)
    constexpr int NTOT = HOUT / 8;
    if (w < NTOT) {
        int c16 = lane & 15, g = lane >> 4, koff = g * 8;
        const u16* pah = &sA[0][c16 * STR + koff];
        const u16* pal = &sA[1][c16 * STR + koff];
        const u16* pbh = Bh + (size_t)(w * 16 + c16) * 128 + koff;
        const u16* pbl = Bl + (size_t)(w * 16 + c16) * 128 + koff;
        f32x4 acc = (f32x4){0.f, 0.f, 0.f, 0.f};
#pragma unroll
        for (int kk = 0; kk < 128; kk += 32) {
            bf16x8 ah = *(const bf16x8*)(pah + kk);
            bf16x8 al = *(const bf16x8*)(pal + kk);
            bf16x8 bh = *(const bf16x8*)(pbh + kk);
            bf16x8 bl = *(const bf16x8*)(pbl + kk);
            acc = __builtin_amdgcn_mfma_f32_16x16x32_bf16(ah, bh, acc, 0, 0, 0);
            acc = __builtin_amdgcn_mfma_f32_16x16x32_bf16(al, bh, acc, 0, 0, 0);
            acc = __builtin_amdgcn_mfma_f32_16x16x32_bf16(ah, bl, acc, 0, 0, 0);
        }
        if (w < NTOT / 2) {                    // y half -> bf16 (stride YSTR)
            int col = w * 16 + c16;
#pragma unroll
            for (int r = 0; r < 4; ++r)
                yout[(size_t)(m0 + g * 4 + r) * YSTR + col] = f2bf(acc[r]);
        } else {                               // z half -> f32 (stride HOUT)
            int col = (w - NTOT / 2) * 16 + c16;
#pragma unroll
            for (int r = 0; r < 4; ++r)
                zout[(size_t)(m0 + g * 4 + r) * HOUT + col] = acc[r];
        }
    }
    if constexpr (HOUT == 48) {   // zero the y pad cols [48,64)
        if (w == NTOT) {
#pragma unroll
            for (int k = 0; k < 2; ++k) {
                int ii = lane * 2 + k;
                int r = ii >> 3, cc = ii & 7;
                ((u32*)(yout + (size_t)(m0 + r) * YSTR + 48))[cc] = 0u;
            }
        }
    }
}

// ---------------------------------------------------------------------------
// Final: out = LN( sum(partials) + self + z3 ).  y3 [N][64] bf16, z3 [N][48].
// Wave per node; seg = lane&7, pg = lane>>3 (pg<4 read partials).
// ---------------------------------------------------------------------------
__global__ __launch_bounds__(256) void final_reduce_kernel(
    const u16* __restrict__ yself, const float* __restrict__ zin,
    const u16* __restrict__ partial, const float* __restrict__ dis,
    float* __restrict__ out, int N) {
    int node = (blockIdx.x * 256 + threadIdx.x) >> 6;
    int lane = threadIdx.x & 63;
    if (node >= N) return;
    int seg = lane & 7, pg = lane >> 3;

    float a[8];
#pragma unroll
    for (int j = 0; j < 8; ++j) a[j] = 0.f;
    if (pg < 4) {
        int4 v = *(const int4*)(partial + ((size_t)pg * N + node) * 64 + seg * 8);
        a[0] = lo2f(v.x); a[1] = hi2f(v.x);
        a[2] = lo2f(v.y); a[3] = hi2f(v.y);
        a[4] = lo2f(v.z); a[5] = hi2f(v.z);
        a[6] = lo2f(v.w); a[7] = hi2f(v.w);
    }
#pragma unroll
    for (int j = 0; j < 8; ++j) {
        a[j] += __shfl_xor(a[j], 8, 64);
        a[j] += __shfl_xor(a[j], 16, 64);
        a[j] += __shfl_xor(a[j], 32, 64);
    }
    if (pg == 0) {
        float d = dis[node];
        float sw = 2.f * d * d;
        int4 sv = *(const int4*)(yself + (size_t)node * 64 + seg * 8);
        float4 z0 = {0.f, 0.f, 0.f, 0.f}, z1 = {0.f, 0.f, 0.f, 0.f};
        if (seg < 6) {
            z0 = *(const float4*)(zin + (size_t)node * 48 + seg * 8);
            z1 = *(const float4*)(zin + (size_t)node * 48 + seg * 8 + 4);
        }
        a[0] += z0.x + sw * lo2f(sv.x); a[1] += z0.y + sw * hi2f(sv.x);
        a[2] += z0.z + sw * lo2f(sv.y); a[3] += z0.w + sw * hi2f(sv.y);
        a[4] += z1.x + sw * lo2f(sv.z); a[5] += z1.y + sw * hi2f(sv.z);
        a[6] += z1.z + sw * lo2f(sv.w); a[7] += z1.w + sw * hi2f(sv.w);
    }
    // LN over the 47 real cols
    float s1 = 0.f, s2 = 0.f;
#pragma unroll
    for (int j = 0; j < 8; ++j) {
        int col = seg * 8 + j;
        if (col < OUT_F) { s1 += a[j]; s2 += a[j] * a[j]; }
    }
#pragma unroll
    for (int m = 4; m >= 1; m >>= 1) {
        s1 += __shfl_xor(s1, m, 64);
        s2 += __shfl_xor(s2, m, 64);
    }
    float mu  = s1 * (1.0f / OUT_F);
    float var = s2 * (1.0f / OUT_F) - mu * mu;
    float inv = rsqrtf(var + 1e-5f);

    if (pg == 0) {
#pragma unroll
        for (int j = 0; j < 8; ++j) {
            int col = seg * 8 + j;
            if (col < OUT_F)
                out[(size_t)node * OUT_F + col] = (a[j] - mu) * inv;
        }
    }
}

// ---------------------------------------------------------------------------
extern "C" void kernel_launch(void* const* d_in, const int* in_sizes, int n_in,
                              void* d_out, int out_size, void* d_ws, size_t ws_size,
                              hipStream_t stream) {
    const float* x  = (const float*)d_in[0];
    const int*   ei = (const int*)d_in[1];
    const float* W1 = (const float*)d_in[2];
    const float* W2 = (const float*)d_in[3];
    const float* W3 = (const float*)d_in[4];
    float* out = (float*)d_out;

    const int N = in_sizes[0] / IN_F;   // 50000
    const int E = in_sizes[1] / 2;      // 800000
    const int M = N * NPART;            // 200000 bins
    const int* erow = ei;
    const int* ecol = ei + E;

    char* p = (char*)d_ws;
    auto alloc = [&](size_t bytes) -> void* {
        void* r = (void*)p;
        p += (bytes + 255) & ~(size_t)255;
        return r;
    };
    int*   cnt4  = (int*)  alloc((size_t)M * 4);
    int*   offs4 = (int*)  alloc((size_t)(M + 1) * 4);
    int*   fill4 = (int*)  alloc((size_t)M * 4);
    float* dis   = (float*)alloc((size_t)N * 4);
    int*   bsum  = (int*)  alloc((size_t)256 * 4);
    int*   ccol4 = (int*)  alloc((size_t)(E + 16) * 4);
    float* cw4   = (float*)alloc((size_t)(E + 16) * 4);
    u16*   ya    = (u16*)  alloc((size_t)N * 128 * 2);
    float* za    = (float*)alloc((size_t)N * 128 * 4);
    u16*   yb    = (u16*)  alloc((size_t)N * 128 * 2);
    float* zb    = (float*)alloc((size_t)N * 128 * 4);
    u16*   part  = (u16*)  alloc((size_t)NPART * N * 128 * 2);   // 51.2 MB
    u16*   B1h   = (u16*)  alloc((size_t)256 * 128 * 2);
    u16*   B1l   = (u16*)  alloc((size_t)256 * 128 * 2);
    u16*   B2h   = (u16*)  alloc((size_t)256 * 128 * 2);
    u16*   B2l   = (u16*)  alloc((size_t)256 * 128 * 2);
    u16*   B3h   = (u16*)  alloc((size_t)96 * 128 * 2);
    u16*   B3l   = (u16*)  alloc((size_t)96 * 128 * 2);

    hipMemsetAsync(cnt4,  0, (size_t)M * 4, stream);
    hipMemsetAsync(fill4, 0, (size_t)M * 4, stream);

    const int egrid = (E + 255) / 256;        // 3125
    const int nb1k  = (M + 1023) / 1024;      // 196

    count4_kernel<<<egrid, 256, 0, stream>>>(erow, ecol, E, cnt4);
    dis_kernel<<<(N + 255) / 256, 256, 0, stream>>>(cnt4, dis, N);
    scan_bsum_kernel<<<nb1k, 1024, 0, stream>>>(cnt4, bsum, M);
    scan_mid_kernel<<<1, 256, 0, stream>>>(bsum, nb1k);
    scan_offs_kernel<<<nb1k, 1024, 0, stream>>>(cnt4, bsum, offs4, M, E);
    fill4_kernel<<<egrid, 256, 0, stream>>>(erow, ecol, E, offs4, fill4, dis, ccol4, cw4);

    wtprep_all_kernel<<<608, 128, 0, stream>>>(W1, W2, W3, B1h, B1l, B2h, B2l, B3h, B3l);

    const int gblocks = N / 16;               // 3125 (16-node tiles)
    const int pblocks = (N / 4 / 2) * 8;      // 50000: (tile-pair, q) -> XCD pinning

    // layer 1: x -> (y1,z1)
    xgemm_kernel<<<gblocks, 1024, 0, stream>>>(x, B1h, B1l, ya, za, N);

    // layer 2: partial = A_p . y1 ; h1 = LN(sum + self + z1) ; -> (y2,z2)
    pgather_kernel<64><<<pblocks, 256, 0, stream>>>(ya, offs4, ccol4, cw4, part, N);
    reduce_ln_gemm_kernel<128, 128><<<gblocks, 1024, 0, stream>>>(
        ya, za, part, dis, B2h, B2l, yb, zb, N);

    // layer 3: same on y2 -> (y3 [N][64] padded, z3 [N][48])
    pgather_kernel<64><<<pblocks, 256, 0, stream>>>(yb, offs4, ccol4, cw4, part, N);
    reduce_ln_gemm_kernel<48, 64><<<gblocks, 1024, 0, stream>>>(
        yb, zb, part, dis, B3h, B3l, ya, za, N);

    // final: partials over y3, then out = LN(sum + self + z3)
    pgather_kernel<32><<<pblocks, 256, 0, stream>>>(ya, offs4, ccol4, cw4, part, N);
    final_reduce_kernel<<<(N * 64 + 255) / 256, 256, 0, stream>>>(
        ya, za, part, dis, out, N);
}

// Round 7
// 333.852 us; speedup vs baseline: 1.2737x; 1.2737x over previous
//
#include <hip/hip_runtime.h>

#define IN_F   100
#define HID_F  128
#define OUT_F  47

typedef short bf16x8 __attribute__((ext_vector_type(8)));
typedef short bf16x4 __attribute__((ext_vector_type(4)));
typedef float f32x4  __attribute__((ext_vector_type(4)));
typedef unsigned short u16;
typedef unsigned int   u32;

__device__ __forceinline__ u16 f2bf(float f) {
    u32 u = __float_as_uint(f);
    u += 0x7FFFu + ((u >> 16) & 1u);           // RNE
    return (u16)(u >> 16);
}
__device__ __forceinline__ float bf2f(u16 b) { return __uint_as_float(((u32)b) << 16); }
__device__ __forceinline__ float lo2f(u32 v) { return __uint_as_float(v << 16); }
__device__ __forceinline__ float hi2f(u32 v) { return __uint_as_float(v & 0xFFFF0000u); }

__device__ __forceinline__ void fma8(float* a, float wt, int4 v) {
    a[0] += wt * lo2f(v.x); a[1] += wt * hi2f(v.x);
    a[2] += wt * lo2f(v.y); a[3] += wt * hi2f(v.y);
    a[4] += wt * lo2f(v.z); a[5] += wt * hi2f(v.z);
    a[6] += wt * lo2f(v.w); a[7] += wt * hi2f(v.w);
}

// ---------------------------------------------------------------------------
// CSR build
// ---------------------------------------------------------------------------
__global__ void count_kernel(const int* __restrict__ row, int E, int* __restrict__ cnt) {
    int e = blockIdx.x * blockDim.x + threadIdx.x;
    if (e < E) atomicAdd(&cnt[row[e]], 1);
}

__global__ void scan_bsum_kernel(const int* __restrict__ cnt, int* __restrict__ bsum, int N) {
    __shared__ int red[4];
    int i = blockIdx.x * 256 + threadIdx.x;
    int v = (i < N) ? cnt[i] : 0;
#pragma unroll
    for (int m = 32; m >= 1; m >>= 1) v += __shfl_xor(v, m, 64);
    if ((threadIdx.x & 63) == 0) red[threadIdx.x >> 6] = v;
    __syncthreads();
    if (threadIdx.x == 0) bsum[blockIdx.x] = red[0] + red[1] + red[2] + red[3];
}

__global__ void scan_mid_kernel(int* __restrict__ bsum, int nb) {
    __shared__ int s[256];
    int t = threadIdx.x;
    int v = (t < nb) ? bsum[t] : 0;
    s[t] = v;
    __syncthreads();
    for (int o = 1; o < 256; o <<= 1) {
        int u = (t >= o) ? s[t - o] : 0;
        __syncthreads();
        s[t] += u;
        __syncthreads();
    }
    if (t < nb) bsum[t] = s[t] - v;     // exclusive
}

__global__ void scan_offs_kernel(const int* __restrict__ cnt, const int* __restrict__ bsum,
                                 int* __restrict__ offs, float* __restrict__ dis, int N, int E) {
    __shared__ int s[256];
    int b = blockIdx.x, t = threadIdx.x;
    int i = b * 256 + t;
    int v = (i < N) ? cnt[i] : 0;
    s[t] = v;
    __syncthreads();
    for (int o = 1; o < 256; o <<= 1) {
        int u = (t >= o) ? s[t - o] : 0;
        __syncthreads();
        s[t] += u;
        __syncthreads();
    }
    if (i < N) {
        offs[i] = bsum[b] + s[t] - v;
        dis[i]  = rsqrtf((float)v + 1.0f);   // +1 self loop
    }
    if (b == 0 && t == 0) offs[N] = E;
}

__global__ void fill_kernel(const int* __restrict__ row, const int* __restrict__ col, int E,
                            const int* __restrict__ offs, int* __restrict__ fill,
                            const float* __restrict__ dis,
                            int* __restrict__ ccol, float* __restrict__ cw) {
    int e = blockIdx.x * blockDim.x + threadIdx.x;
    if (e < E) {
        int r = row[e], c = col[e];
        int pos = offs[r] + atomicAdd(&fill[r], 1);
        ccol[pos] = c;
        cw[pos]   = dis[r] * dis[c];
    }
}

// ---------------------------------------------------------------------------
// Weight prep: B = [ Wa^T ; Wx^T ] as [2*NPAD][128] hi/lo
// ---------------------------------------------------------------------------
__global__ void wtprep_all_kernel(const float* __restrict__ W1, const float* __restrict__ W2,
                                  const float* __restrict__ W3,
                                  u16* __restrict__ B1h, u16* __restrict__ B1l,
                                  u16* __restrict__ B2h, u16* __restrict__ B2l,
                                  u16* __restrict__ B3h, u16* __restrict__ B3l) {
    int b = blockIdx.x, k = threadIdx.x;   // k: 0..127
    const float* W; u16 *Bh, *Bl; int KSRC, NSRC, NPAD, n;
    if (b < 256)      { W = W1; Bh = B1h; Bl = B1l; KSRC = IN_F;  NSRC = HID_F; NPAD = 128; n = b; }
    else if (b < 512) { W = W2; Bh = B2h; Bl = B2l; KSRC = HID_F; NSRC = HID_F; NPAD = 128; n = b - 256; }
    else              { W = W3; Bh = B3h; Bl = B3l; KSRC = HID_F; NSRC = OUT_F; NPAD = 48;  n = b - 512; }
    int half = (n >= NPAD) ? 1 : 0;
    int cc = n - half * NPAD;
    float v = (cc < NSRC && k < KSRC) ? W[(size_t)(half * KSRC + k) * NSRC + cc] : 0.f;
    u16 h = f2bf(v);
    Bh[(size_t)n * 128 + k] = h;
    Bl[(size_t)n * 128 + k] = f2bf(v - bf2f(h));
}

// ---------------------------------------------------------------------------
// Fused per-16-node-tile kernel.
//   gather (!FIRST): wave w = node m0+w; lane=(eg=lane>>4, seg=lane&15);
//     yz-in rows are [256] bf16: y=cols 0..127 (gathered), z=cols 128..255.
//     agg = sum_e w_e*y[col_e] + 2*dis^2*y[self] + z ; LN+ReLU -> hi/lo LDS.
//   GEMM: wave w -> output tile w. SWAPPED mfma operands: D[row=n][col=node],
//     so lane (g,c16) holds node=c16, 4 consecutive out-cols g*4+r -> one
//     packed 8B bf16x4 store.
// HOUT=128: out [N][256] (y|z interleaved by tile index, cols w*16).
// HOUT=48:  out [N][128]: y cols 0..47 (pad 48..63), z cols 64..111 (pad ..127).
// ---------------------------------------------------------------------------
template <int HOUT, int OSTR, bool FIRST>
__global__ __launch_bounds__(1024) void fused_kernel(
    const float* __restrict__ x, const u16* __restrict__ yzin,
    const int* __restrict__ offs, const int* __restrict__ ccol,
    const float* __restrict__ cw, const float* __restrict__ dis,
    const u16* __restrict__ Bh, const u16* __restrict__ Bl,
    u16* __restrict__ yzout, int N) {
    constexpr int STR = 152;
    __shared__ u16 sA[2][16 * STR];
    int tid = threadIdx.x;
    int m0 = blockIdx.x * 16;
    int w = tid >> 6, lane = tid & 63;

    if (FIRST) {
#pragma unroll
        for (int idx = tid; idx < 16 * 128; idx += 1024) {
            int r = idx >> 7, c = idx & 127;
            float v = (c < IN_F) ? x[(size_t)(m0 + r) * IN_F + c] : 0.f;
            u16 h = f2bf(v);
            sA[0][r * STR + c] = h;
            sA[1][r * STR + c] = f2bf(v - bf2f(h));
        }
    } else {
        int node = m0 + w;
        int seg = lane & 15, eg = lane >> 4;
        float a[8];
        if (eg == 0) {     // z + diag-enhanced self loop (both bf16, one row)
            float d = dis[node];
            float sw = 2.f * d * d;
            int4 sv = *(const int4*)(yzin + (size_t)node * 256 + seg * 8);
            int4 zv = *(const int4*)(yzin + (size_t)node * 256 + 128 + seg * 8);
            a[0] = lo2f(zv.x) + sw * lo2f(sv.x); a[1] = hi2f(zv.x) + sw * hi2f(sv.x);
            a[2] = lo2f(zv.y) + sw * lo2f(sv.y); a[3] = hi2f(zv.y) + sw * hi2f(sv.y);
            a[4] = lo2f(zv.z) + sw * lo2f(sv.z); a[5] = hi2f(zv.z) + sw * hi2f(sv.z);
            a[6] = lo2f(zv.w) + sw * lo2f(sv.w); a[7] = hi2f(zv.w) + sw * hi2f(sv.w);
        } else {
#pragma unroll
            for (int j = 0; j < 8; ++j) a[j] = 0.f;
        }

        int s = offs[node], e = offs[node + 1];
#pragma unroll 4
        for (int p0 = s; p0 < e; p0 += 4) {
            int idx = p0 + eg;
            int idc = min(idx, e - 1);
            int c   = ccol[idc];
            float wt = (idx < e) ? cw[idc] : 0.f;
            int4 v = *(const int4*)(yzin + (size_t)c * 256 + seg * 8);
            fma8(a, wt, v);
        }

        // reduce the 4 edge-groups
#pragma unroll
        for (int j = 0; j < 8; ++j) {
            a[j] += __shfl_xor(a[j], 16, 64);
            a[j] += __shfl_xor(a[j], 32, 64);
        }
        // LN stats over 128 cols
        float s1 = 0.f, s2 = 0.f;
#pragma unroll
        for (int j = 0; j < 8; ++j) { s1 += a[j]; s2 += a[j] * a[j]; }
#pragma unroll
        for (int m = 8; m >= 1; m >>= 1) {
            s1 += __shfl_xor(s1, m, 64);
            s2 += __shfl_xor(s2, m, 64);
        }
        float mu  = s1 * (1.0f / 128);
        float var = s2 * (1.0f / 128) - mu * mu;
        float inv = rsqrtf(var + 1e-5f);
        if (eg == 0) {
            bf16x8 hv, lv;
#pragma unroll
            for (int j = 0; j < 8; ++j) {
                float o = fmaxf((a[j] - mu) * inv, 0.f);
                u16 h = f2bf(o);
                hv[j] = (short)h;
                lv[j] = (short)f2bf(o - bf2f(h));
            }
            *(bf16x8*)(&sA[0][w * STR + seg * 8]) = hv;
            *(bf16x8*)(&sA[1][w * STR + seg * 8]) = lv;
        }
    }
    __syncthreads();

    // GEMM phase, swapped operands: D[row = out-col n][col = node]
    constexpr int NTOT = HOUT / 8;
    if (w < NTOT) {
        int c16 = lane & 15, g = lane >> 4, koff = g * 8;
        const u16* pah = &sA[0][c16 * STR + koff];
        const u16* pal = &sA[1][c16 * STR + koff];
        const u16* pbh = Bh + (size_t)(w * 16 + c16) * 128 + koff;
        const u16* pbl = Bl + (size_t)(w * 16 + c16) * 128 + koff;
        f32x4 acc = (f32x4){0.f, 0.f, 0.f, 0.f};
#pragma unroll
        for (int kk = 0; kk < 128; kk += 32) {
            bf16x8 ah = *(const bf16x8*)(pah + kk);
            bf16x8 al = *(const bf16x8*)(pal + kk);
            bf16x8 bh = *(const bf16x8*)(pbh + kk);
            bf16x8 bl = *(const bf16x8*)(pbl + kk);
            acc = __builtin_amdgcn_mfma_f32_16x16x32_bf16(bh, ah, acc, 0, 0, 0);
            acc = __builtin_amdgcn_mfma_f32_16x16x32_bf16(bh, al, acc, 0, 0, 0);
            acc = __builtin_amdgcn_mfma_f32_16x16x32_bf16(bl, ah, acc, 0, 0, 0);
        }
        // lane holds node = m0+c16, out-cols colbase..colbase+3
        int colbase = w * 16 + g * 4;
        if (HOUT == 48 && w >= 3) colbase += 16;   // z half starts at col 64
        bf16x4 o;
        o[0] = (short)f2bf(acc[0]);
        o[1] = (short)f2bf(acc[1]);
        o[2] = (short)f2bf(acc[2]);
        o[3] = (short)f2bf(acc[3]);
        *(bf16x4*)(yzout + (size_t)(m0 + c16) * OSTR + colbase) = o;
    }
    if constexpr (HOUT == 48) {
        if (w == NTOT) {   // zero pads: cols [48,64) and [112,128) of 16 rows
#pragma unroll
            for (int k = 0; k < 2; ++k) {
                int idx = lane * 2 + k;            // 0..127
                int r = idx >> 3, rem = idx & 7;
                int col = 48 + (rem >> 2) * 64 + (rem & 3) * 4;
                bf16x4 zz = (bf16x4){0, 0, 0, 0};
                *(bf16x4*)(yzout + (size_t)(m0 + r) * OSTR + col) = zz;
            }
        }
    }
}

// ---------------------------------------------------------------------------
// Final: out = LN( gather(y3) + self + z3 ).  yz3 [N][128] bf16:
// y cols 0..47 (pad..63), z cols 64..111.  Wave per node; seg=lane&7 (8x int4
// over cols 0..63), eg=lane>>3 (8 edges in flight).
// ---------------------------------------------------------------------------
__global__ __launch_bounds__(256) void final_reduce_kernel(
    const u16* __restrict__ yz, const int* __restrict__ offs,
    const int* __restrict__ ccol, const float* __restrict__ cw,
    const float* __restrict__ dis, float* __restrict__ out, int N) {
    int node = (blockIdx.x * 256 + threadIdx.x) >> 6;
    int lane = threadIdx.x & 63;
    if (node >= N) return;
    int seg = lane & 7, eg = lane >> 3;

    float a[8];
    if (eg == 0) {
        float d = dis[node];
        float sw = 2.f * d * d;
        int4 sv = *(const int4*)(yz + (size_t)node * 128 + seg * 8);
        int4 zv = *(const int4*)(yz + (size_t)node * 128 + 64 + seg * 8);
        a[0] = lo2f(zv.x) + sw * lo2f(sv.x); a[1] = hi2f(zv.x) + sw * hi2f(sv.x);
        a[2] = lo2f(zv.y) + sw * lo2f(sv.y); a[3] = hi2f(zv.y) + sw * hi2f(sv.y);
        a[4] = lo2f(zv.z) + sw * lo2f(sv.z); a[5] = hi2f(zv.z) + sw * hi2f(sv.z);
        a[6] = lo2f(zv.w) + sw * lo2f(sv.w); a[7] = hi2f(zv.w) + sw * hi2f(sv.w);
    } else {
#pragma unroll
        for (int j = 0; j < 8; ++j) a[j] = 0.f;
    }

    int s = offs[node], e = offs[node + 1];
#pragma unroll 4
    for (int p0 = s; p0 < e; p0 += 8) {
        int idx = p0 + eg;
        int idc = min(idx, e - 1);
        int c   = ccol[idc];
        float wt = (idx < e) ? cw[idc] : 0.f;
        int4 v = *(const int4*)(yz + (size_t)c * 128 + seg * 8);
        fma8(a, wt, v);
    }

#pragma unroll
    for (int j = 0; j < 8; ++j) {
        a[j] += __shfl_xor(a[j], 8, 64);
        a[j] += __shfl_xor(a[j], 16, 64);
        a[j] += __shfl_xor(a[j], 32, 64);
    }
    // LN over the 47 real cols
    float s1 = 0.f, s2 = 0.f;
#pragma unroll
    for (int j = 0; j < 8; ++j) {
        int col = seg * 8 + j;
        if (col < OUT_F) { s1 += a[j]; s2 += a[j] * a[j]; }
    }
#pragma unroll
    for (int m = 4; m >= 1; m >>= 1) {
        s1 += __shfl_xor(s1, m, 64);
        s2 += __shfl_xor(s2, m, 64);
    }
    float mu  = s1 * (1.0f / OUT_F);
    float var = s2 * (1.0f / OUT_F) - mu * mu;
    float inv = rsqrtf(var + 1e-5f);

    if (eg == 0) {
#pragma unroll
        for (int j = 0; j < 8; ++j) {
            int col = seg * 8 + j;
            if (col < OUT_F)
                out[(size_t)node * OUT_F + col] = (a[j] - mu) * inv;
        }
    }
}

// ---------------------------------------------------------------------------
extern "C" void kernel_launch(void* const* d_in, const int* in_sizes, int n_in,
                              void* d_out, int out_size, void* d_ws, size_t ws_size,
                              hipStream_t stream) {
    const float* x  = (const float*)d_in[0];
    const int*   ei = (const int*)d_in[1];
    const float* W1 = (const float*)d_in[2];
    const float* W2 = (const float*)d_in[3];
    const float* W3 = (const float*)d_in[4];
    float* out = (float*)d_out;

    const int N = in_sizes[0] / IN_F;   // 50000
    const int E = in_sizes[1] / 2;      // 800000
    const int* erow = ei;
    const int* ecol = ei + E;

    char* p = (char*)d_ws;
    auto alloc = [&](size_t bytes) -> void* {
        void* r = (void*)p;
        p += (bytes + 255) & ~(size_t)255;
        return r;
    };
    int*   cnt  = (int*)  alloc((size_t)N * 4);
    int*   offs = (int*)  alloc((size_t)(N + 1) * 4);
    int*   fill = (int*)  alloc((size_t)N * 4);
    float* dis  = (float*)alloc((size_t)N * 4);
    int*   bsum = (int*)  alloc((size_t)256 * 4);
    int*   ccol = (int*)  alloc((size_t)(E + 16) * 4);
    float* cw   = (float*)alloc((size_t)(E + 16) * 4);
    u16*   yzA  = (u16*)  alloc((size_t)N * 256 * 2);   // 25.6 MB
    u16*   yzB  = (u16*)  alloc((size_t)N * 256 * 2);
    u16*   yzC  = (u16*)  alloc((size_t)N * 128 * 2);   // layer-3 out
    u16*   B1h  = (u16*)  alloc((size_t)256 * 128 * 2);
    u16*   B1l  = (u16*)  alloc((size_t)256 * 128 * 2);
    u16*   B2h  = (u16*)  alloc((size_t)256 * 128 * 2);
    u16*   B2l  = (u16*)  alloc((size_t)256 * 128 * 2);
    u16*   B3h  = (u16*)  alloc((size_t)96 * 128 * 2);
    u16*   B3l  = (u16*)  alloc((size_t)96 * 128 * 2);

    hipMemsetAsync(cnt,  0, (size_t)N * 4, stream);
    hipMemsetAsync(fill, 0, (size_t)N * 4, stream);

    const int egrid = (E + 255) / 256;       // 3125
    const int nb    = (N + 255) / 256;       // 196

    count_kernel<<<egrid, 256, 0, stream>>>(erow, E, cnt);
    scan_bsum_kernel<<<nb, 256, 0, stream>>>(cnt, bsum, N);
    scan_mid_kernel<<<1, 256, 0, stream>>>(bsum, nb);
    scan_offs_kernel<<<nb, 256, 0, stream>>>(cnt, bsum, offs, dis, N, E);
    fill_kernel<<<egrid, 256, 0, stream>>>(erow, ecol, E, offs, fill, dis, ccol, cw);

    wtprep_all_kernel<<<608, 128, 0, stream>>>(W1, W2, W3, B1h, B1l, B2h, B2l, B3h, B3l);

    const int gblocks = N / 16;               // 3125

    // layer 1: x -> yz1 [N][256]
    fused_kernel<128, 256, true><<<gblocks, 1024, 0, stream>>>(
        x, nullptr, offs, ccol, cw, dis, B1h, B1l, yzA, N);
    // layer 2: gather(yzA) -> h1 -> yz2 [N][256]
    fused_kernel<128, 256, false><<<gblocks, 1024, 0, stream>>>(
        nullptr, yzA, offs, ccol, cw, dis, B2h, B2l, yzB, N);
    // layer 3: gather(yzB) -> h2 -> yz3 [N][128]
    fused_kernel<48, 128, false><<<gblocks, 1024, 0, stream>>>(
        nullptr, yzB, offs, ccol, cw, dis, B3h, B3l, yzC, N);
    // final: out = LN(gather(yzC.y) + self + yzC.z)
    final_reduce_kernel<<<(N * 64 + 255) / 256, 256, 0, stream>>>(
        yzC, offs, ccol, cw, dis, out, N);
}

// Round 8
// 330.746 us; speedup vs baseline: 1.2857x; 1.0094x over previous
//
#include <hip/hip_runtime.h>

#define IN_F   100
#define HID_F  128
#define OUT_F  47

typedef short bf16x8 __attribute__((ext_vector_type(8)));
typedef short bf16x4 __attribute__((ext_vector_type(4)));
typedef float f32x4  __attribute__((ext_vector_type(4)));
typedef unsigned short u16;
typedef unsigned int   u32;

__device__ __forceinline__ u16 f2bf(float f) {
    u32 u = __float_as_uint(f);
    u += 0x7FFFu + ((u >> 16) & 1u);           // RNE
    return (u16)(u >> 16);
}
__device__ __forceinline__ float bf2f(u16 b) { return __uint_as_float(((u32)b) << 16); }
__device__ __forceinline__ float lo2f(u32 v) { return __uint_as_float(v << 16); }
__device__ __forceinline__ float hi2f(u32 v) { return __uint_as_float(v & 0xFFFF0000u); }

__device__ __forceinline__ void fma8(float* a, float wt, int4 v) {
    a[0] += wt * lo2f(v.x); a[1] += wt * hi2f(v.x);
    a[2] += wt * lo2f(v.y); a[3] += wt * hi2f(v.y);
    a[4] += wt * lo2f(v.z); a[5] += wt * hi2f(v.z);
    a[6] += wt * lo2f(v.w); a[7] += wt * hi2f(v.w);
}

// ---------------------------------------------------------------------------
// CSR build
// ---------------------------------------------------------------------------
__global__ void count_kernel(const int* __restrict__ row, int E, int* __restrict__ cnt) {
    int e = blockIdx.x * blockDim.x + threadIdx.x;
    if (e < E) atomicAdd(&cnt[row[e]], 1);
}

__global__ void scan_bsum_kernel(const int* __restrict__ cnt, int* __restrict__ bsum, int N) {
    __shared__ int red[4];
    int i = blockIdx.x * 256 + threadIdx.x;
    int v = (i < N) ? cnt[i] : 0;
#pragma unroll
    for (int m = 32; m >= 1; m >>= 1) v += __shfl_xor(v, m, 64);
    if ((threadIdx.x & 63) == 0) red[threadIdx.x >> 6] = v;
    __syncthreads();
    if (threadIdx.x == 0) bsum[blockIdx.x] = red[0] + red[1] + red[2] + red[3];
}

__global__ void scan_mid_kernel(int* __restrict__ bsum, int nb) {
    __shared__ int s[256];
    int t = threadIdx.x;
    int v = (t < nb) ? bsum[t] : 0;
    s[t] = v;
    __syncthreads();
    for (int o = 1; o < 256; o <<= 1) {
        int u = (t >= o) ? s[t - o] : 0;
        __syncthreads();
        s[t] += u;
        __syncthreads();
    }
    if (t < nb) bsum[t] = s[t] - v;     // exclusive
}

__global__ void scan_offs_kernel(const int* __restrict__ cnt, const int* __restrict__ bsum,
                                 int* __restrict__ offs, float* __restrict__ dis, int N, int E) {
    __shared__ int s[256];
    int b = blockIdx.x, t = threadIdx.x;
    int i = b * 256 + t;
    int v = (i < N) ? cnt[i] : 0;
    s[t] = v;
    __syncthreads();
    for (int o = 1; o < 256; o <<= 1) {
        int u = (t >= o) ? s[t - o] : 0;
        __syncthreads();
        s[t] += u;
        __syncthreads();
    }
    if (i < N) {
        offs[i] = bsum[b] + s[t] - v;
        dis[i]  = rsqrtf((float)v + 1.0f);   // +1 self loop
    }
    if (b == 0 && t == 0) offs[N] = E;
}

__global__ void fill_kernel(const int* __restrict__ row, const int* __restrict__ col, int E,
                            const int* __restrict__ offs, int* __restrict__ fill,
                            const float* __restrict__ dis, int2* __restrict__ cwp) {
    int e = blockIdx.x * blockDim.x + threadIdx.x;
    if (e < E) {
        int r = row[e], c = col[e];
        int pos = offs[r] + atomicAdd(&fill[r], 1);
        int2 q;
        q.x = c;
        q.y = __float_as_int(dis[r] * dis[c]);
        cwp[pos] = q;
    }
}

// ---------------------------------------------------------------------------
// Weight prep: B = [ Wa^T ; Wx^T ] as [2*NPAD][128] hi/lo
// ---------------------------------------------------------------------------
__global__ void wtprep_all_kernel(const float* __restrict__ W1, const float* __restrict__ W2,
                                  const float* __restrict__ W3,
                                  u16* __restrict__ B1h, u16* __restrict__ B1l,
                                  u16* __restrict__ B2h, u16* __restrict__ B2l,
                                  u16* __restrict__ B3h, u16* __restrict__ B3l) {
    int b = blockIdx.x, k = threadIdx.x;   // k: 0..127
    const float* W; u16 *Bh, *Bl; int KSRC, NSRC, NPAD, n;
    if (b < 256)      { W = W1; Bh = B1h; Bl = B1l; KSRC = IN_F;  NSRC = HID_F; NPAD = 128; n = b; }
    else if (b < 512) { W = W2; Bh = B2h; Bl = B2l; KSRC = HID_F; NSRC = HID_F; NPAD = 128; n = b - 256; }
    else              { W = W3; Bh = B3h; Bl = B3l; KSRC = HID_F; NSRC = OUT_F; NPAD = 48;  n = b - 512; }
    int half = (n >= NPAD) ? 1 : 0;
    int cc = n - half * NPAD;
    float v = (cc < NSRC && k < KSRC) ? W[(size_t)(half * KSRC + k) * NSRC + cc] : 0.f;
    u16 h = f2bf(v);
    Bh[(size_t)n * 128 + k] = h;
    Bl[(size_t)n * 128 + k] = f2bf(v - bf2f(h));
}

// ---------------------------------------------------------------------------
// Gather + LayerNorm + ReLU (standalone, NO barrier; wave per node).
// yzin rows [256] bf16: y = cols 0..127 (gathered), z = cols 128..255.
// h = LN(sum_e w_e*y[col_e] + 2*dis^2*y[self] + z), ReLU, hi/lo split ->
// hout [N][256]: cols 0..127 = hi, 128..255 = lo.
// lane = (eg = lane>>4: 4 concurrent edges, seg = lane&15: 16B segment).
// ---------------------------------------------------------------------------
__global__ __launch_bounds__(256) void gather_ln_kernel(
    const u16* __restrict__ yzin, const int* __restrict__ offs,
    const int2* __restrict__ cwp, const float* __restrict__ dis,
    u16* __restrict__ hout, int N) {
    int node = (blockIdx.x * 256 + threadIdx.x) >> 6;
    int lane = threadIdx.x & 63;
    if (node >= N) return;
    int seg = lane & 15, eg = lane >> 4;

    float a[8];
    if (eg == 0) {     // z + diag-enhanced self loop
        float d = dis[node];
        float sw = 2.f * d * d;
        int4 sv = *(const int4*)(yzin + (size_t)node * 256 + seg * 8);
        int4 zv = *(const int4*)(yzin + (size_t)node * 256 + 128 + seg * 8);
        a[0] = lo2f(zv.x) + sw * lo2f(sv.x); a[1] = hi2f(zv.x) + sw * hi2f(sv.x);
        a[2] = lo2f(zv.y) + sw * lo2f(sv.y); a[3] = hi2f(zv.y) + sw * hi2f(sv.y);
        a[4] = lo2f(zv.z) + sw * lo2f(sv.z); a[5] = hi2f(zv.z) + sw * hi2f(sv.z);
        a[6] = lo2f(zv.w) + sw * lo2f(sv.w); a[7] = hi2f(zv.w) + sw * hi2f(sv.w);
    } else {
#pragma unroll
        for (int j = 0; j < 8; ++j) a[j] = 0.f;
    }

    int s = offs[node], e = offs[node + 1];
#pragma unroll 4
    for (int p0 = s; p0 < e; p0 += 4) {
        int idx = p0 + eg;
        int idc = min(idx, e - 1);
        int2 q = cwp[idc];
        float wt = (idx < e) ? __int_as_float(q.y) : 0.f;
        int4 v = *(const int4*)(yzin + (size_t)q.x * 256 + seg * 8);
        fma8(a, wt, v);
    }

    // reduce the 4 edge-groups
#pragma unroll
    for (int j = 0; j < 8; ++j) {
        a[j] += __shfl_xor(a[j], 16, 64);
        a[j] += __shfl_xor(a[j], 32, 64);
    }
    // LN stats over 128 cols
    float s1 = 0.f, s2 = 0.f;
#pragma unroll
    for (int j = 0; j < 8; ++j) { s1 += a[j]; s2 += a[j] * a[j]; }
#pragma unroll
    for (int m = 8; m >= 1; m >>= 1) {
        s1 += __shfl_xor(s1, m, 64);
        s2 += __shfl_xor(s2, m, 64);
    }
    float mu  = s1 * (1.0f / 128);
    float var = s2 * (1.0f / 128) - mu * mu;
    float inv = rsqrtf(var + 1e-5f);
    if (eg == 0) {
        bf16x8 hv, lv;
#pragma unroll
        for (int j = 0; j < 8; ++j) {
            float o = fmaxf((a[j] - mu) * inv, 0.f);
            u16 h = f2bf(o);
            hv[j] = (short)h;
            lv[j] = (short)f2bf(o - bf2f(h));
        }
        *(bf16x8*)(hout + (size_t)node * 256 + seg * 8)       = hv;
        *(bf16x8*)(hout + (size_t)node * 256 + 128 + seg * 8) = lv;
    }
}

// ---------------------------------------------------------------------------
// GEMM (mid layers): h [N][256] (hi|lo) -> LDS, [y|z] = h @ B^T.
// Swapped mfma operands: lane (g,c16) holds node = m0+c16, out-cols g*4..+3,
// one packed 8B bf16x4 store.
// HOUT=128: out [N][256]; HOUT=48: out [N][128] (y 0..47 pad..63, z 64..111 pad..127).
// ---------------------------------------------------------------------------
template <int HOUT, int OSTR>
__global__ __launch_bounds__(1024) void gemm_mid_kernel(
    const u16* __restrict__ hin,
    const u16* __restrict__ Bh, const u16* __restrict__ Bl,
    u16* __restrict__ yzout, int N) {
    constexpr int STR = 152;
    __shared__ u16 sA[2][16 * STR];
    int tid = threadIdx.x;
    int m0 = blockIdx.x * 16;
    int w = tid >> 6, lane = tid & 63;

    if (tid < 512) {   // stage 16 rows x 256 u16 (hi|lo) as bf16x8 chunks
        int r = tid >> 5, cs = tid & 31;
        bf16x8 v = *(const bf16x8*)(hin + (size_t)(m0 + r) * 256 + cs * 8);
        if (cs < 16) *(bf16x8*)(&sA[0][r * STR + cs * 8]) = v;
        else         *(bf16x8*)(&sA[1][r * STR + (cs - 16) * 8]) = v;
    }
    __syncthreads();

    constexpr int NTOT = HOUT / 8;
    if (w < NTOT) {
        int c16 = lane & 15, g = lane >> 4, koff = g * 8;
        const u16* pah = &sA[0][c16 * STR + koff];
        const u16* pal = &sA[1][c16 * STR + koff];
        const u16* pbh = Bh + (size_t)(w * 16 + c16) * 128 + koff;
        const u16* pbl = Bl + (size_t)(w * 16 + c16) * 128 + koff;
        f32x4 acc = (f32x4){0.f, 0.f, 0.f, 0.f};
#pragma unroll
        for (int kk = 0; kk < 128; kk += 32) {
            bf16x8 ah = *(const bf16x8*)(pah + kk);
            bf16x8 al = *(const bf16x8*)(pal + kk);
            bf16x8 bh = *(const bf16x8*)(pbh + kk);
            bf16x8 bl = *(const bf16x8*)(pbl + kk);
            acc = __builtin_amdgcn_mfma_f32_16x16x32_bf16(bh, ah, acc, 0, 0, 0);
            acc = __builtin_amdgcn_mfma_f32_16x16x32_bf16(bh, al, acc, 0, 0, 0);
            acc = __builtin_amdgcn_mfma_f32_16x16x32_bf16(bl, ah, acc, 0, 0, 0);
        }
        int colbase = w * 16 + g * 4;
        if (HOUT == 48 && w >= 3) colbase += 16;   // z half starts at col 64
        bf16x4 o;
        o[0] = (short)f2bf(acc[0]);
        o[1] = (short)f2bf(acc[1]);
        o[2] = (short)f2bf(acc[2]);
        o[3] = (short)f2bf(acc[3]);
        *(bf16x4*)(yzout + (size_t)(m0 + c16) * OSTR + colbase) = o;
    }
    if constexpr (HOUT == 48) {
        if (w == NTOT) {   // zero pads: cols [48,64) and [112,128)
#pragma unroll
            for (int k = 0; k < 2; ++k) {
                int idx = lane * 2 + k;
                int r = idx >> 3, rem = idx & 7;
                int col = 48 + (rem >> 2) * 64 + (rem & 3) * 4;
                bf16x4 zz = (bf16x4){0, 0, 0, 0};
                *(bf16x4*)(yzout + (size_t)(m0 + r) * OSTR + col) = zz;
            }
        }
    }
}

// ---------------------------------------------------------------------------
// Layer 1: x f32 -> hi/lo LDS -> [y|z] = x @ B1^T -> yz1 [N][256]
// ---------------------------------------------------------------------------
__global__ __launch_bounds__(1024) void xgemm_kernel(
    const float* __restrict__ x,
    const u16* __restrict__ Bh, const u16* __restrict__ Bl,
    u16* __restrict__ yzout, int N) {
    constexpr int STR = 152;
    __shared__ u16 sA[2][16 * STR];
    int tid = threadIdx.x;
    int m0 = blockIdx.x * 16;
    int w = tid >> 6, lane = tid & 63;

#pragma unroll
    for (int idx = tid; idx < 16 * 128; idx += 1024) {
        int r = idx >> 7, c = idx & 127;
        float v = (c < IN_F) ? x[(size_t)(m0 + r) * IN_F + c] : 0.f;
        u16 h = f2bf(v);
        sA[0][r * STR + c] = h;
        sA[1][r * STR + c] = f2bf(v - bf2f(h));
    }
    __syncthreads();

    {
        int c16 = lane & 15, g = lane >> 4, koff = g * 8;
        const u16* pah = &sA[0][c16 * STR + koff];
        const u16* pal = &sA[1][c16 * STR + koff];
        const u16* pbh = Bh + (size_t)(w * 16 + c16) * 128 + koff;
        const u16* pbl = Bl + (size_t)(w * 16 + c16) * 128 + koff;
        f32x4 acc = (f32x4){0.f, 0.f, 0.f, 0.f};
#pragma unroll
        for (int kk = 0; kk < 128; kk += 32) {
            bf16x8 ah = *(const bf16x8*)(pah + kk);
            bf16x8 al = *(const bf16x8*)(pal + kk);
            bf16x8 bh = *(const bf16x8*)(pbh + kk);
            bf16x8 bl = *(const bf16x8*)(pbl + kk);
            acc = __builtin_amdgcn_mfma_f32_16x16x32_bf16(bh, ah, acc, 0, 0, 0);
            acc = __builtin_amdgcn_mfma_f32_16x16x32_bf16(bh, al, acc, 0, 0, 0);
            acc = __builtin_amdgcn_mfma_f32_16x16x32_bf16(bl, ah, acc, 0, 0, 0);
        }
        int colbase = w * 16 + g * 4;
        bf16x4 o;
        o[0] = (short)f2bf(acc[0]);
        o[1] = (short)f2bf(acc[1]);
        o[2] = (short)f2bf(acc[2]);
        o[3] = (short)f2bf(acc[3]);
        *(bf16x4*)(yzout + (size_t)(m0 + c16) * 256 + colbase) = o;
    }
}

// ---------------------------------------------------------------------------
// Final: out = LN( gather(y3) + self + z3 ).  yz3 [N][128] bf16:
// y cols 0..47 (pad..63), z cols 64..111.  Wave per node; seg=lane&7, eg=lane>>3.
// ---------------------------------------------------------------------------
__global__ __launch_bounds__(256) void final_reduce_kernel(
    const u16* __restrict__ yz, const int* __restrict__ offs,
    const int2* __restrict__ cwp, const float* __restrict__ dis,
    float* __restrict__ out, int N) {
    int node = (blockIdx.x * 256 + threadIdx.x) >> 6;
    int lane = threadIdx.x & 63;
    if (node >= N) return;
    int seg = lane & 7, eg = lane >> 3;

    float a[8];
    if (eg == 0) {
        float d = dis[node];
        float sw = 2.f * d * d;
        int4 sv = *(const int4*)(yz + (size_t)node * 128 + seg * 8);
        int4 zv = *(const int4*)(yz + (size_t)node * 128 + 64 + seg * 8);
        a[0] = lo2f(zv.x) + sw * lo2f(sv.x); a[1] = hi2f(zv.x) + sw * hi2f(sv.x);
        a[2] = lo2f(zv.y) + sw * lo2f(sv.y); a[3] = hi2f(zv.y) + sw * hi2f(sv.y);
        a[4] = lo2f(zv.z) + sw * lo2f(sv.z); a[5] = hi2f(zv.z) + sw * hi2f(sv.z);
        a[6] = lo2f(zv.w) + sw * lo2f(sv.w); a[7] = hi2f(zv.w) + sw * hi2f(sv.w);
    } else {
#pragma unroll
        for (int j = 0; j < 8; ++j) a[j] = 0.f;
    }

    int s = offs[node], e = offs[node + 1];
#pragma unroll 4
    for (int p0 = s; p0 < e; p0 += 8) {
        int idx = p0 + eg;
        int idc = min(idx, e - 1);
        int2 q = cwp[idc];
        float wt = (idx < e) ? __int_as_float(q.y) : 0.f;
        int4 v = *(const int4*)(yz + (size_t)q.x * 128 + seg * 8);
        fma8(a, wt, v);
    }

#pragma unroll
    for (int j = 0; j < 8; ++j) {
        a[j] += __shfl_xor(a[j], 8, 64);
        a[j] += __shfl_xor(a[j], 16, 64);
        a[j] += __shfl_xor(a[j], 32, 64);
    }
    // LN over the 47 real cols
    float s1 = 0.f, s2 = 0.f;
#pragma unroll
    for (int j = 0; j < 8; ++j) {
        int col = seg * 8 + j;
        if (col < OUT_F) { s1 += a[j]; s2 += a[j] * a[j]; }
    }
#pragma unroll
    for (int m = 4; m >= 1; m >>= 1) {
        s1 += __shfl_xor(s1, m, 64);
        s2 += __shfl_xor(s2, m, 64);
    }
    float mu  = s1 * (1.0f / OUT_F);
    float var = s2 * (1.0f / OUT_F) - mu * mu;
    float inv = rsqrtf(var + 1e-5f);

    if (eg == 0) {
#pragma unroll
        for (int j = 0; j < 8; ++j) {
            int col = seg * 8 + j;
            if (col < OUT_F)
                out[(size_t)node * OUT_F + col] = (a[j] - mu) * inv;
        }
    }
}

// ---------------------------------------------------------------------------
extern "C" void kernel_launch(void* const* d_in, const int* in_sizes, int n_in,
                              void* d_out, int out_size, void* d_ws, size_t ws_size,
                              hipStream_t stream) {
    const float* x  = (const float*)d_in[0];
    const int*   ei = (const int*)d_in[1];
    const float* W1 = (const float*)d_in[2];
    const float* W2 = (const float*)d_in[3];
    const float* W3 = (const float*)d_in[4];
    float* out = (float*)d_out;

    const int N = in_sizes[0] / IN_F;   // 50000
    const int E = in_sizes[1] / 2;      // 800000
    const int* erow = ei;
    const int* ecol = ei + E;

    char* p = (char*)d_ws;
    auto alloc = [&](size_t bytes) -> void* {
        void* r = (void*)p;
        p += (bytes + 255) & ~(size_t)255;
        return r;
    };
    int*   cnt  = (int*)  alloc((size_t)N * 4);
    int*   offs = (int*)  alloc((size_t)(N + 1) * 4);
    int*   fill = (int*)  alloc((size_t)N * 4);
    float* dis  = (float*)alloc((size_t)N * 4);
    int*   bsum = (int*)  alloc((size_t)256 * 4);
    int2*  cwp  = (int2*) alloc((size_t)(E + 16) * 8);
    u16*   yzA  = (u16*)  alloc((size_t)N * 256 * 2);   // 25.6 MB
    u16*   yzB  = (u16*)  alloc((size_t)N * 256 * 2);
    u16*   yzC  = (u16*)  alloc((size_t)N * 128 * 2);
    u16*   hbuf = (u16*)  alloc((size_t)N * 256 * 2);   // h hi|lo
    u16*   B1h  = (u16*)  alloc((size_t)256 * 128 * 2);
    u16*   B1l  = (u16*)  alloc((size_t)256 * 128 * 2);
    u16*   B2h  = (u16*)  alloc((size_t)256 * 128 * 2);
    u16*   B2l  = (u16*)  alloc((size_t)256 * 128 * 2);
    u16*   B3h  = (u16*)  alloc((size_t)96 * 128 * 2);
    u16*   B3l  = (u16*)  alloc((size_t)96 * 128 * 2);

    hipMemsetAsync(cnt,  0, (size_t)N * 4, stream);
    hipMemsetAsync(fill, 0, (size_t)N * 4, stream);

    const int egrid = (E + 255) / 256;       // 3125
    const int nb    = (N + 255) / 256;       // 196

    count_kernel<<<egrid, 256, 0, stream>>>(erow, E, cnt);
    scan_bsum_kernel<<<nb, 256, 0, stream>>>(cnt, bsum, N);
    scan_mid_kernel<<<1, 256, 0, stream>>>(bsum, nb);
    scan_offs_kernel<<<nb, 256, 0, stream>>>(cnt, bsum, offs, dis, N, E);
    fill_kernel<<<egrid, 256, 0, stream>>>(erow, ecol, E, offs, fill, dis, cwp);

    wtprep_all_kernel<<<608, 128, 0, stream>>>(W1, W2, W3, B1h, B1l, B2h, B2l, B3h, B3l);

    const int gblocks = N / 16;               // 3125
    const int wblocks = (N * 64 + 255) / 256; // 12500 (wave per node)

    // layer 1: x -> yz1
    xgemm_kernel<<<gblocks, 1024, 0, stream>>>(x, B1h, B1l, yzA, N);
    // layer 2
    gather_ln_kernel<<<wblocks, 256, 0, stream>>>(yzA, offs, cwp, dis, hbuf, N);
    gemm_mid_kernel<128, 256><<<gblocks, 1024, 0, stream>>>(hbuf, B2h, B2l, yzB, N);
    // layer 3
    gather_ln_kernel<<<wblocks, 256, 0, stream>>>(yzB, offs, cwp, dis, hbuf, N);
    gemm_mid_kernel<48, 128><<<gblocks, 1024, 0, stream>>>(hbuf, B3h, B3l, yzC, N);
    // final
    final_reduce_kernel<<<wblocks, 256, 0, stream>>>(yzC, offs, cwp, dis, out, N);
}

// Round 10
// 330.352 us; speedup vs baseline: 1.2872x; 1.0012x over previous
//
#include <hip/hip_runtime.h>

#define IN_F   100
#define HID_F  128
#define OUT_F  47

typedef short bf16x8 __attribute__((ext_vector_type(8)));
typedef short bf16x4 __attribute__((ext_vector_type(4)));
typedef float f32x4  __attribute__((ext_vector_type(4)));
typedef unsigned short u16;
typedef unsigned int   u32;

__device__ __forceinline__ u16 f2bf(float f) {
    u32 u = __float_as_uint(f);
    u += 0x7FFFu + ((u >> 16) & 1u);           // RNE
    return (u16)(u >> 16);
}
__device__ __forceinline__ float bf2f(u16 b) { return __uint_as_float(((u32)b) << 16); }
__device__ __forceinline__ float lo2f(u32 v) { return __uint_as_float(v << 16); }
__device__ __forceinline__ float hi2f(u32 v) { return __uint_as_float(v & 0xFFFF0000u); }

__device__ __forceinline__ void fma8(float* a, float wt, int4 v) {
    a[0] += wt * lo2f(v.x); a[1] += wt * hi2f(v.x);
    a[2] += wt * lo2f(v.y); a[3] += wt * hi2f(v.y);
    a[4] += wt * lo2f(v.z); a[5] += wt * hi2f(v.z);
    a[6] += wt * lo2f(v.w); a[7] += wt * hi2f(v.w);
}

// ---------------------------------------------------------------------------
// CSR build
// ---------------------------------------------------------------------------
__global__ void count_kernel(const int* __restrict__ row, int E, int* __restrict__ cnt) {
    int e = blockIdx.x * blockDim.x + threadIdx.x;
    if (e < E) atomicAdd(&cnt[row[e]], 1);
}

__global__ void scan_bsum_kernel(const int* __restrict__ cnt, int* __restrict__ bsum, int N) {
    __shared__ int red[4];
    int i = blockIdx.x * 256 + threadIdx.x;
    int v = (i < N) ? cnt[i] : 0;
#pragma unroll
    for (int m = 32; m >= 1; m >>= 1) v += __shfl_xor(v, m, 64);
    if ((threadIdx.x & 63) == 0) red[threadIdx.x >> 6] = v;
    __syncthreads();
    if (threadIdx.x == 0) bsum[blockIdx.x] = red[0] + red[1] + red[2] + red[3];
}

__global__ void scan_mid_kernel(int* __restrict__ bsum, int nb) {
    __shared__ int s[256];
    int t = threadIdx.x;
    int v = (t < nb) ? bsum[t] : 0;
    s[t] = v;
    __syncthreads();
    for (int o = 1; o < 256; o <<= 1) {
        int u = (t >= o) ? s[t - o] : 0;
        __syncthreads();
        s[t] += u;
        __syncthreads();
    }
    if (t < nb) bsum[t] = s[t] - v;     // exclusive
}

__global__ void scan_offs_kernel(const int* __restrict__ cnt, const int* __restrict__ bsum,
                                 int* __restrict__ offs, float* __restrict__ dis, int N, int E) {
    __shared__ int s[256];
    int b = blockIdx.x, t = threadIdx.x;
    int i = b * 256 + t;
    int v = (i < N) ? cnt[i] : 0;
    s[t] = v;
    __syncthreads();
    for (int o = 1; o < 256; o <<= 1) {
        int u = (t >= o) ? s[t - o] : 0;
        __syncthreads();
        s[t] += u;
        __syncthreads();
    }
    if (i < N) {
        offs[i] = bsum[b] + s[t] - v;
        dis[i]  = rsqrtf((float)v + 1.0f);   // +1 self loop
    }
    if (b == 0 && t == 0) offs[N] = E;
}

__global__ void fill_kernel(const int* __restrict__ row, const int* __restrict__ col, int E,
                            const int* __restrict__ offs, int* __restrict__ fill,
                            const float* __restrict__ dis, int2* __restrict__ cwp) {
    int e = blockIdx.x * blockDim.x + threadIdx.x;
    if (e < E) {
        int r = row[e], c = col[e];
        int pos = offs[r] + atomicAdd(&fill[r], 1);
        int2 q;
        q.x = c;
        q.y = __float_as_int(dis[r] * dis[c]);
        cwp[pos] = q;
    }
}

// ---------------------------------------------------------------------------
// Weight prep: B = [ Wa^T ; Wx^T ] as [2*NPAD][128] hi/lo
// ---------------------------------------------------------------------------
__global__ void wtprep_all_kernel(const float* __restrict__ W1, const float* __restrict__ W2,
                                  const float* __restrict__ W3,
                                  u16* __restrict__ B1h, u16* __restrict__ B1l,
                                  u16* __restrict__ B2h, u16* __restrict__ B2l,
                                  u16* __restrict__ B3h, u16* __restrict__ B3l) {
    int b = blockIdx.x, k = threadIdx.x;   // k: 0..127
    const float* W; u16 *Bh, *Bl; int KSRC, NSRC, NPAD, n;
    if (b < 256)      { W = W1; Bh = B1h; Bl = B1l; KSRC = IN_F;  NSRC = HID_F; NPAD = 128; n = b; }
    else if (b < 512) { W = W2; Bh = B2h; Bl = B2l; KSRC = HID_F; NSRC = HID_F; NPAD = 128; n = b - 256; }
    else              { W = W3; Bh = B3h; Bl = B3l; KSRC = HID_F; NSRC = OUT_F; NPAD = 48;  n = b - 512; }
    int half = (n >= NPAD) ? 1 : 0;
    int cc = n - half * NPAD;
    float v = (cc < NSRC && k < KSRC) ? W[(size_t)(half * KSRC + k) * NSRC + cc] : 0.f;
    u16 h = f2bf(v);
    Bh[(size_t)n * 128 + k] = h;
    Bl[(size_t)n * 128 + k] = f2bf(v - bf2f(h));
}

// ---------------------------------------------------------------------------
// Gather + LayerNorm + ReLU (standalone, NO barrier; wave per node).
// yzin rows [256] bf16: y = cols 0..127 (gathered), z = cols 128..255.
// hout [N][256]: cols 0..127 = hi, 128..255 = lo.
// ---------------------------------------------------------------------------
__global__ __launch_bounds__(256) void gather_ln_kernel(
    const u16* __restrict__ yzin, const int* __restrict__ offs,
    const int2* __restrict__ cwp, const float* __restrict__ dis,
    u16* __restrict__ hout, int N) {
    int node = (blockIdx.x * 256 + threadIdx.x) >> 6;
    int lane = threadIdx.x & 63;
    if (node >= N) return;
    int seg = lane & 15, eg = lane >> 4;

    float a[8];
    if (eg == 0) {     // z + diag-enhanced self loop
        float d = dis[node];
        float sw = 2.f * d * d;
        int4 sv = *(const int4*)(yzin + (size_t)node * 256 + seg * 8);
        int4 zv = *(const int4*)(yzin + (size_t)node * 256 + 128 + seg * 8);
        a[0] = lo2f(zv.x) + sw * lo2f(sv.x); a[1] = hi2f(zv.x) + sw * hi2f(sv.x);
        a[2] = lo2f(zv.y) + sw * lo2f(sv.y); a[3] = hi2f(zv.y) + sw * hi2f(sv.y);
        a[4] = lo2f(zv.z) + sw * lo2f(sv.z); a[5] = hi2f(zv.z) + sw * hi2f(sv.z);
        a[6] = lo2f(zv.w) + sw * lo2f(sv.w); a[7] = hi2f(zv.w) + sw * hi2f(sv.w);
    } else {
#pragma unroll
        for (int j = 0; j < 8; ++j) a[j] = 0.f;
    }

    int s = offs[node], e = offs[node + 1];
#pragma unroll 4
    for (int p0 = s; p0 < e; p0 += 4) {
        int idx = p0 + eg;
        int idc = min(idx, e - 1);
        int2 q = cwp[idc];
        float wt = (idx < e) ? __int_as_float(q.y) : 0.f;
        int4 v = *(const int4*)(yzin + (size_t)q.x * 256 + seg * 8);
        fma8(a, wt, v);
    }

#pragma unroll
    for (int j = 0; j < 8; ++j) {
        a[j] += __shfl_xor(a[j], 16, 64);
        a[j] += __shfl_xor(a[j], 32, 64);
    }
    float s1 = 0.f, s2 = 0.f;
#pragma unroll
    for (int j = 0; j < 8; ++j) { s1 += a[j]; s2 += a[j] * a[j]; }
#pragma unroll
    for (int m = 8; m >= 1; m >>= 1) {
        s1 += __shfl_xor(s1, m, 64);
        s2 += __shfl_xor(s2, m, 64);
    }
    float mu  = s1 * (1.0f / 128);
    float var = s2 * (1.0f / 128) - mu * mu;
    float inv = rsqrtf(var + 1e-5f);
    if (eg == 0) {
        bf16x8 hv, lv;
#pragma unroll
        for (int j = 0; j < 8; ++j) {
            float o = fmaxf((a[j] - mu) * inv, 0.f);
            u16 h = f2bf(o);
            hv[j] = (short)h;
            lv[j] = (short)f2bf(o - bf2f(h));
        }
        *(bf16x8*)(hout + (size_t)node * 256 + seg * 8)       = hv;
        *(bf16x8*)(hout + (size_t)node * 256 + 128 + seg * 8) = lv;
    }
}

// ---------------------------------------------------------------------------
// Shared GEMM core: A tile in sA (hi/lo, 16 rows x 128, stride GSTR), 4 waves,
// wave w computes tiles {w, w+4, ...}. A frags hoisted to registers (8x b128).
// Swapped mfma: lane (g,c16) -> node m0+c16, out-cols base+g*4 (8B store).
// ---------------------------------------------------------------------------
#define GSTR 152

template <int HOUT, int OSTR>
__device__ __forceinline__ void gemm_core(
    const u16* sA0, const u16* sA1,
    const u16* __restrict__ Bh, const u16* __restrict__ Bl,
    u16* __restrict__ yzout, int m0, int tid) {
    int w = tid >> 6, lane = tid & 63;
    int c16 = lane & 15, g = lane >> 4, koff = g * 8;

    // hoist A fragments (this lane's node row, 4 k-slices, hi+lo)
    bf16x8 ah[4], al[4];
#pragma unroll
    for (int k = 0; k < 4; ++k) {
        ah[k] = *(const bf16x8*)(sA0 + c16 * GSTR + koff + k * 32);
        al[k] = *(const bf16x8*)(sA1 + c16 * GSTR + koff + k * 32);
    }

    constexpr int NTOT = HOUT / 8;
#pragma unroll
    for (int t = w; t < NTOT; t += 4) {
        const u16* pbh = Bh + (size_t)(t * 16 + c16) * 128 + koff;
        const u16* pbl = Bl + (size_t)(t * 16 + c16) * 128 + koff;
        f32x4 acc = (f32x4){0.f, 0.f, 0.f, 0.f};
#pragma unroll
        for (int k = 0; k < 4; ++k) {
            bf16x8 bh = *(const bf16x8*)(pbh + k * 32);
            bf16x8 bl = *(const bf16x8*)(pbl + k * 32);
            acc = __builtin_amdgcn_mfma_f32_16x16x32_bf16(bh, ah[k], acc, 0, 0, 0);
            acc = __builtin_amdgcn_mfma_f32_16x16x32_bf16(bh, al[k], acc, 0, 0, 0);
            acc = __builtin_amdgcn_mfma_f32_16x16x32_bf16(bl, ah[k], acc, 0, 0, 0);
        }
        int colbase = t * 16 + g * 4;
        if (HOUT == 48 && t >= 3) colbase += 16;   // z half starts at col 64
        bf16x4 o;
        o[0] = (short)f2bf(acc[0]);
        o[1] = (short)f2bf(acc[1]);
        o[2] = (short)f2bf(acc[2]);
        o[3] = (short)f2bf(acc[3]);
        *(bf16x4*)(yzout + (size_t)(m0 + c16) * OSTR + colbase) = o;
    }
}

// ---------------------------------------------------------------------------
// Layer 1: x f32 -> hi/lo LDS -> [y|z] = x @ B1^T -> yz1 [N][256]
// 256 threads; staging via float4.  528 chunks = 400 data (25/row) + 128 pad
// (8/row covering cols 100..131) — FIX: was 512, leaving rows 14-15 un-padded.
// ---------------------------------------------------------------------------
__global__ __launch_bounds__(256) void xgemm_kernel(
    const float* __restrict__ x,
    const u16* __restrict__ Bh, const u16* __restrict__ Bl,
    u16* __restrict__ yzout, int N) {
    __shared__ u16 sA[2][16 * GSTR];
    int tid = threadIdx.x;
    int m0 = blockIdx.x * 16;

#pragma unroll
    for (int i = tid; i < 528; i += 256) {
        int r, c;
        float4 v;
        if (i < 400) {
            r = i / 25; c = (i % 25) * 4;
            v = *(const float4*)(x + (size_t)(m0 + r) * IN_F + c);
        } else {
            int j = i - 400;                     // 0..127
            r = j >> 3; c = 100 + (j & 7) * 4;   // 16 rows x 8 chunks, cols 100..131
            v = (float4){0.f, 0.f, 0.f, 0.f};
        }
        u16 h0 = f2bf(v.x), h1 = f2bf(v.y), h2 = f2bf(v.z), h3 = f2bf(v.w);
        bf16x4 hh = (bf16x4){(short)h0, (short)h1, (short)h2, (short)h3};
        bf16x4 ll = (bf16x4){(short)f2bf(v.x - bf2f(h0)), (short)f2bf(v.y - bf2f(h1)),
                             (short)f2bf(v.z - bf2f(h2)), (short)f2bf(v.w - bf2f(h3))};
        *(bf16x4*)(&sA[0][r * GSTR + c]) = hh;
        *(bf16x4*)(&sA[1][r * GSTR + c]) = ll;
    }
    __syncthreads();
    gemm_core<128, 256>(&sA[0][0], &sA[1][0], Bh, Bl, yzout, m0, tid);
}

// ---------------------------------------------------------------------------
// Mid/last GEMM: h [N][256] (hi|lo) -> LDS -> [y|z] = h @ B^T
// ---------------------------------------------------------------------------
template <int HOUT, int OSTR>
__global__ __launch_bounds__(256) void gemm_mid_kernel(
    const u16* __restrict__ hin,
    const u16* __restrict__ Bh, const u16* __restrict__ Bl,
    u16* __restrict__ yzout, int N) {
    __shared__ u16 sA[2][16 * GSTR];
    int tid = threadIdx.x;
    int m0 = blockIdx.x * 16;

#pragma unroll
    for (int i = tid; i < 512; i += 256) {   // 16 rows x 32 bf16x8 chunks
        int r = i >> 5, cs = i & 31;
        bf16x8 v = *(const bf16x8*)(hin + (size_t)(m0 + r) * 256 + cs * 8);
        if (cs < 16) *(bf16x8*)(&sA[0][r * GSTR + cs * 8]) = v;
        else         *(bf16x8*)(&sA[1][r * GSTR + (cs - 16) * 8]) = v;
    }
    if constexpr (HOUT == 48) {
        if (tid < 128) {   // zero pads: cols [48,64) and [112,128) of 16 rows
            int r = tid >> 3, rem = tid & 7;
            int col = 48 + (rem >> 2) * 64 + (rem & 3) * 4;
            bf16x4 zz = (bf16x4){0, 0, 0, 0};
            *(bf16x4*)(yzout + (size_t)(m0 + r) * OSTR + col) = zz;
        }
    }
    __syncthreads();
    gemm_core<HOUT, OSTR>(&sA[0][0], &sA[1][0], Bh, Bl, yzout, m0, tid);
}

// ---------------------------------------------------------------------------
// Final: out = LN( gather(y3) + self + z3 ).  yz3 [N][128] bf16:
// y cols 0..47 (pad..63), z cols 64..111.  Wave per node; seg=lane&7, eg=lane>>3.
// ---------------------------------------------------------------------------
__global__ __launch_bounds__(256) void final_reduce_kernel(
    const u16* __restrict__ yz, const int* __restrict__ offs,
    const int2* __restrict__ cwp, const float* __restrict__ dis,
    float* __restrict__ out, int N) {
    int node = (blockIdx.x * 256 + threadIdx.x) >> 6;
    int lane = threadIdx.x & 63;
    if (node >= N) return;
    int seg = lane & 7, eg = lane >> 3;

    float a[8];
    if (eg == 0) {
        float d = dis[node];
        float sw = 2.f * d * d;
        int4 sv = *(const int4*)(yz + (size_t)node * 128 + seg * 8);
        int4 zv = *(const int4*)(yz + (size_t)node * 128 + 64 + seg * 8);
        a[0] = lo2f(zv.x) + sw * lo2f(sv.x); a[1] = hi2f(zv.x) + sw * hi2f(sv.x);
        a[2] = lo2f(zv.y) + sw * lo2f(sv.y); a[3] = hi2f(zv.y) + sw * hi2f(sv.y);
        a[4] = lo2f(zv.z) + sw * lo2f(sv.z); a[5] = hi2f(zv.z) + sw * hi2f(sv.z);
        a[6] = lo2f(zv.w) + sw * lo2f(sv.w); a[7] = hi2f(zv.w) + sw * hi2f(sv.w);
    } else {
#pragma unroll
        for (int j = 0; j < 8; ++j) a[j] = 0.f;
    }

    int s = offs[node], e = offs[node + 1];
#pragma unroll 4
    for (int p0 = s; p0 < e; p0 += 8) {
        int idx = p0 + eg;
        int idc = min(idx, e - 1);
        int2 q = cwp[idc];
        float wt = (idx < e) ? __int_as_float(q.y) : 0.f;
        int4 v = *(const int4*)(yz + (size_t)q.x * 128 + seg * 8);
        fma8(a, wt, v);
    }

#pragma unroll
    for (int j = 0; j < 8; ++j) {
        a[j] += __shfl_xor(a[j], 8, 64);
        a[j] += __shfl_xor(a[j], 16, 64);
        a[j] += __shfl_xor(a[j], 32, 64);
    }
    float s1 = 0.f, s2 = 0.f;
#pragma unroll
    for (int j = 0; j < 8; ++j) {
        int col = seg * 8 + j;
        if (col < OUT_F) { s1 += a[j]; s2 += a[j] * a[j]; }
    }
#pragma unroll
    for (int m = 4; m >= 1; m >>= 1) {
        s1 += __shfl_xor(s1, m, 64);
        s2 += __shfl_xor(s2, m, 64);
    }
    float mu  = s1 * (1.0f / OUT_F);
    float var = s2 * (1.0f / OUT_F) - mu * mu;
    float inv = rsqrtf(var + 1e-5f);

    if (eg == 0) {
#pragma unroll
        for (int j = 0; j < 8; ++j) {
            int col = seg * 8 + j;
            if (col < OUT_F)
                out[(size_t)node * OUT_F + col] = (a[j] - mu) * inv;
        }
    }
}

// ---------------------------------------------------------------------------
extern "C" void kernel_launch(void* const* d_in, const int* in_sizes, int n_in,
                              void* d_out, int out_size, void* d_ws, size_t ws_size,
                              hipStream_t stream) {
    const float* x  = (const float*)d_in[0];
    const int*   ei = (const int*)d_in[1];
    const float* W1 = (const float*)d_in[2];
    const float* W2 = (const float*)d_in[3];
    const float* W3 = (const float*)d_in[4];
    float* out = (float*)d_out;

    const int N = in_sizes[0] / IN_F;   // 50000
    const int E = in_sizes[1] / 2;      // 800000
    const int* erow = ei;
    const int* ecol = ei + E;

    char* p = (char*)d_ws;
    auto alloc = [&](size_t bytes) -> void* {
        void* r = (void*)p;
        p += (bytes + 255) & ~(size_t)255;
        return r;
    };
    int*   cnt  = (int*)  alloc((size_t)N * 4);
    int*   offs = (int*)  alloc((size_t)(N + 1) * 4);
    int*   fill = (int*)  alloc((size_t)N * 4);
    float* dis  = (float*)alloc((size_t)N * 4);
    int*   bsum = (int*)  alloc((size_t)256 * 4);
    int2*  cwp  = (int2*) alloc((size_t)(E + 16) * 8);
    u16*   yzA  = (u16*)  alloc((size_t)N * 256 * 2);   // 25.6 MB
    u16*   yzB  = (u16*)  alloc((size_t)N * 256 * 2);
    u16*   yzC  = (u16*)  alloc((size_t)N * 128 * 2);
    u16*   hbuf = (u16*)  alloc((size_t)N * 256 * 2);   // h hi|lo
    u16*   B1h  = (u16*)  alloc((size_t)256 * 128 * 2);
    u16*   B1l  = (u16*)  alloc((size_t)256 * 128 * 2);
    u16*   B2h  = (u16*)  alloc((size_t)256 * 128 * 2);
    u16*   B2l  = (u16*)  alloc((size_t)256 * 128 * 2);
    u16*   B3h  = (u16*)  alloc((size_t)96 * 128 * 2);
    u16*   B3l  = (u16*)  alloc((size_t)96 * 128 * 2);

    hipMemsetAsync(cnt,  0, (size_t)N * 4, stream);
    hipMemsetAsync(fill, 0, (size_t)N * 4, stream);

    const int egrid = (E + 255) / 256;       // 3125
    const int nb    = (N + 255) / 256;       // 196

    count_kernel<<<egrid, 256, 0, stream>>>(erow, E, cnt);
    scan_bsum_kernel<<<nb, 256, 0, stream>>>(cnt, bsum, N);
    scan_mid_kernel<<<1, 256, 0, stream>>>(bsum, nb);
    scan_offs_kernel<<<nb, 256, 0, stream>>>(cnt, bsum, offs, dis, N, E);
    fill_kernel<<<egrid, 256, 0, stream>>>(erow, ecol, E, offs, fill, dis, cwp);

    wtprep_all_kernel<<<608, 128, 0, stream>>>(W1, W2, W3, B1h, B1l, B2h, B2l, B3h, B3l);

    const int gblocks = N / 16;               // 3125 (256-thr blocks)
    const int wblocks = (N * 64 + 255) / 256; // 12500 (wave per node)

    // layer 1: x -> yz1
    xgemm_kernel<<<gblocks, 256, 0, stream>>>(x, B1h, B1l, yzA, N);
    // layer 2
    gather_ln_kernel<<<wblocks, 256, 0, stream>>>(yzA, offs, cwp, dis, hbuf, N);
    gemm_mid_kernel<128, 256><<<gblocks, 256, 0, stream>>>(hbuf, B2h, B2l, yzB, N);
    // layer 3
    gather_ln_kernel<<<wblocks, 256, 0, stream>>>(yzB, offs, cwp, dis, hbuf, N);
    gemm_mid_kernel<48, 128><<<gblocks, 256, 0, stream>>>(hbuf, B3h, B3l, yzC, N);
    // final
    final_reduce_kernel<<<wblocks, 256, 0, stream>>>(yzC, offs, cwp, dis, out, N);
}